// Round 4
// baseline (279.584 us; speedup 1.0000x reference)
//
#include <hip/hip_runtime.h>

// Problem constants (match reference)
#define G_     64
#define NK     3
#define NB     64
#define IH     512
#define IW     512
#define NC     3
#define HG_    128
#define HL_    128
#define D_IN_    (NK * G_ * G_ * NC)   // 36864
#define D_SCALE  (G_ * G_ * NC)        // 12288
#define KCH      128                   // d per chunk (96 chunks per scale)
#define NCHUNK   (D_IN_ / KCH)         // 288
#define BSPLIT   8                     // R9: batch groups of 8 (was 16)
#define NBLK     (NCHUNK * BSPLIT)     // 2304 blocks (~9/CU)
#define PSTRIDE  (NB * HG_)            // 8192 floats per chunk-slice of P

// R5: atomics were the floor -> stage-1 writes private partials.
// R6: GEMV blocked 16-FMA-per-W1-load. 288.5 -> 278.2 us.
// R8: F=4-first LLC priming + spread reduce: neutral (fused not BW-bound).
// R9 (this round): fused is latency-bound at ~4 blocks/CU (VGPR>64 halves
//     residency). BSPLIT 8, grid 2304, __launch_bounds__(256,8) forcing
//     VGPR<=64, GEMV as 2 batch-quads x 4 d-quarters (unroll 1, ~50 live
//     regs). Total FMA / W-load instruction counts and P size unchanged.
template <int F>
__device__ __forceinline__ void scale_body(
    const float* __restrict__ x, const float* __restrict__ l,
    const float* __restrict__ W1, float* __restrict__ P,
    int roff, int d0, int b0, int chunkGlobal,
    float (&phi_s)[8][KCH], float (&red2)[3][8][HG_], int* cx_s, int* cy_s)
{
    const int tid = threadIdx.x;
    if (tid < 8) {
        float lx = l[(b0 + tid) * 2 + 0];
        float ly = l[(b0 + tid) * 2 + 1];
        // match reference: (0.5*(l+1.0)*512).astype(int32); single rounding at
        // (l+1.0f), *0.5 and *512 exact, trunc toward zero
        cx_s[tid] = (int)((0.5f * (lx + 1.0f)) * 512.0f);
        cy_s[tid] = (int)((0.5f * (ly + 1.0f)) * 512.0f);
    }
    __syncthreads();

    // ---- extraction: thread = (dd, batch-quarter); 4 batches per thread ----
    const int dd   = tid & (KCH - 1);
    const int jb0  = (tid >> 7) * 4;         // 0 or 4
    const int r    = roff + dd;              // within-scale: ((gy*64)+gx)*3+c
    const int gy   = r / (G_ * NC);
    const int rem  = r - gy * (G_ * NC);
    const int gx   = rem / NC;
    const int c    = rem - gx * NC;
    constexpr float inv = 1.0f / (float)(F * F);
    constexpr int JU = (F == 4) ? 2 : 4;     // keep ~16-32 loads in flight

#pragma unroll 1
    for (int jo = 0; jo < 4; jo += JU) {
        float sums[JU];
#pragma unroll
        for (int ji = 0; ji < JU; ++ji) {
            const int jb = jb0 + jo + ji;
            const int b  = b0 + jb;
            const int by = cy_s[jb] - 32 * F + gy * F;
            const int bx = cx_s[jb] - 32 * F + gx * F;
            const float* bimg = x + (size_t)b * (IH * IW * NC) + c;
            float s = 0.0f;
#pragma unroll
            for (int dy = 0; dy < F; ++dy) {
                const int y = by + dy;
                const bool yok = (unsigned)y < (unsigned)IH;
#pragma unroll
                for (int dx = 0; dx < F; ++dx) {
                    const int xx = bx + dx;
                    const bool ok = yok && ((unsigned)xx < (unsigned)IW);
                    s += ok ? bimg[(size_t)y * (IW * NC) + xx * NC] : 0.0f;
                }
            }
            sums[ji] = s;
        }
#pragma unroll
        for (int ji = 0; ji < JU; ++ji)
            phi_s[jb0 + jo + ji][dd] = sums[ji] * inv;
    }
    __syncthreads();

    // ---- GEMV v3: 256 threads = 32 h-quads * (2 batch-quads x 4 d-qtrs) ----
    // Each thread: 4 batches x 4 h over 32 d. One W1 float4 feeds 16 FMAs.
    // Per-wave phi reads are uniform-address (broadcast, conflict-free).
    const int hq  = tid & 31;
    const int h0  = hq * 4;
    const int gg  = tid >> 5;                // 0..7
    const int bg4 = (gg & 1) * 4;            // batch base: 0 or 4
    const int dq  = gg >> 1;                 // d-quarter: 0..3
    const int db  = dq * 32;

    float4 a0 = {0.f, 0.f, 0.f, 0.f};
    float4 a1 = {0.f, 0.f, 0.f, 0.f};
    float4 a2 = {0.f, 0.f, 0.f, 0.f};
    float4 a3 = {0.f, 0.f, 0.f, 0.f};
    const float* wp = W1 + (size_t)(d0 + db) * HG_ + h0;

#pragma unroll 1
    for (int t = 0; t < 8; ++t) {
        const float4 pv0 = *(const float4*)&phi_s[bg4 + 0][db + 4 * t];
        const float4 pv1 = *(const float4*)&phi_s[bg4 + 1][db + 4 * t];
        const float4 pv2 = *(const float4*)&phi_s[bg4 + 2][db + 4 * t];
        const float4 pv3 = *(const float4*)&phi_s[bg4 + 3][db + 4 * t];
#pragma unroll
        for (int u = 0; u < 4; ++u) {
            const float4 wv = *(const float4*)(wp + (size_t)(4 * t + u) * HG_);
            const float p0 = (&pv0.x)[u];
            const float p1 = (&pv1.x)[u];
            const float p2 = (&pv2.x)[u];
            const float p3 = (&pv3.x)[u];
            a0.x = fmaf(p0, wv.x, a0.x); a0.y = fmaf(p0, wv.y, a0.y);
            a0.z = fmaf(p0, wv.z, a0.z); a0.w = fmaf(p0, wv.w, a0.w);
            a1.x = fmaf(p1, wv.x, a1.x); a1.y = fmaf(p1, wv.y, a1.y);
            a1.z = fmaf(p1, wv.z, a1.z); a1.w = fmaf(p1, wv.w, a1.w);
            a2.x = fmaf(p2, wv.x, a2.x); a2.y = fmaf(p2, wv.y, a2.y);
            a2.z = fmaf(p2, wv.z, a2.z); a2.w = fmaf(p2, wv.w, a2.w);
            a3.x = fmaf(p3, wv.x, a3.x); a3.y = fmaf(p3, wv.y, a3.y);
            a3.z = fmaf(p3, wv.z, a3.z); a3.w = fmaf(p3, wv.w, a3.w);
        }
    }

    // d-quarters 1..3 park partials in LDS; d-quarter 0 combines and stores.
    if (dq != 0) {
        *(float4*)&red2[dq - 1][bg4 + 0][h0] = a0;
        *(float4*)&red2[dq - 1][bg4 + 1][h0] = a1;
        *(float4*)&red2[dq - 1][bg4 + 2][h0] = a2;
        *(float4*)&red2[dq - 1][bg4 + 3][h0] = a3;
    }
    __syncthreads();
    if (dq == 0) {
        float* pb = P + (size_t)chunkGlobal * PSTRIDE + (size_t)(b0 + bg4) * HG_ + h0;
#pragma unroll
        for (int q = 0; q < 3; ++q) {
            const float4 r0 = *(const float4*)&red2[q][bg4 + 0][h0];
            const float4 r1 = *(const float4*)&red2[q][bg4 + 1][h0];
            const float4 r2 = *(const float4*)&red2[q][bg4 + 2][h0];
            const float4 r3 = *(const float4*)&red2[q][bg4 + 3][h0];
            a0.x += r0.x; a0.y += r0.y; a0.z += r0.z; a0.w += r0.w;
            a1.x += r1.x; a1.y += r1.y; a1.z += r1.z; a1.w += r1.w;
            a2.x += r2.x; a2.y += r2.y; a2.z += r2.z; a2.w += r2.w;
            a3.x += r3.x; a3.y += r3.y; a3.z += r3.z; a3.w += r3.w;
        }
        *(float4*)(pb + 0 * HG_) = a0;
        *(float4*)(pb + 1 * HG_) = a1;
        *(float4*)(pb + 2 * HG_) = a2;
        *(float4*)(pb + 3 * HG_) = a3;
    }
}

// 2304 blocks: blockIdx = chunkGlobal*8 + bgrp.
// chunkGlobal 0..95 = F4 (dispatches first, primes LLC with the 256^2
// regions), 96..191 = F2, 192..287 = F1. d0 maps each range to its scale's
// rows of W1; P-slice index stays chunkGlobal (sum over slices is order-free).
__global__ __launch_bounds__(256, 8) void fused(
    const float* __restrict__ x, const float* __restrict__ l,
    const float* __restrict__ W1, float* __restrict__ P)
{
    __shared__ float phi_s[8][KCH];      // 4 KB
    __shared__ float red2[3][8][HG_];    // 12 KB (d-quarter combine)
    __shared__ int cx_s[8], cy_s[8];

    const int cg = blockIdx.x >> 3;
    const int b0 = (blockIdx.x & 7) * 8;

    if (cg < 96) {               // F=4 first (largest footprint)
        const int cl = cg;
        scale_body<4>(x, l, W1, P, cl * KCH, 2 * D_SCALE + cl * KCH, b0, cg,
                      phi_s, red2, cx_s, cy_s);
    } else if (cg < 192) {       // F=2
        const int cl = cg - 96;
        scale_body<2>(x, l, W1, P, cl * KCH, D_SCALE + cl * KCH, b0, cg,
                      phi_s, red2, cx_s, cy_s);
    } else {                     // F=1
        const int cl = cg - 192;
        scale_body<1>(x, l, W1, P, cl * KCH, cl * KCH, b0, cg,
                      phi_s, red2, cx_s, cy_s);
    }
}

// Stage 2 v3: 256 blocks = (batch x h-quarter); all CUs participate.
// 256 threads = 32 groups x 8 float4-lanes; each thread sums 9 chunk
// partials (float4), LDS tree combine over groups, 8 threads emit the phi
// quarter, threads 64..95 emit the matching l-branch quarter.
__global__ __launch_bounds__(256) void reduce_epilogue(
    const float* __restrict__ P,
    const float* __restrict__ l,
    const float* __restrict__ b1,
    const float* __restrict__ W2,
    const float* __restrict__ b2,
    float* __restrict__ out)
{
    __shared__ float4 red[32][8];        // 4 KB
    const int b    = blockIdx.x >> 2;
    const int q    = blockIdx.x & 3;     // h-quarter: h0 = q*32
    const int t    = threadIdx.x;
    const int lane = t & 7;              // float4 lane within the 32-h strip
    const int grp  = t >> 3;             // 0..31, 9 chunks each

    const float4* p4 = (const float4*)P
                     + (size_t)(grp * 9) * (PSTRIDE / 4)
                     + (size_t)b * (HG_ / 4) + q * 8 + lane;
    float4 a = make_float4(0.f, 0.f, 0.f, 0.f);
#pragma unroll
    for (int i = 0; i < 9; ++i) {
        const float4 v = p4[(size_t)i * (PSTRIDE / 4)];
        a.x += v.x; a.y += v.y; a.z += v.z; a.w += v.w;
    }
    red[grp][lane] = a;
    __syncthreads();

#pragma unroll
    for (int s = 16; s >= 1; s >>= 1) {
        if (grp < s) {
            const float4 o = red[grp + s][lane];
            float4 m = red[grp][lane];
            m.x += o.x; m.y += o.y; m.z += o.z; m.w += o.w;
            red[grp][lane] = m;
        }
        __syncthreads();
    }

    if (t < 8) {
        const float4 a2 = red[0][t];
        const float4 bb = ((const float4*)b1)[q * 8 + t];
        float4 o;
        o.x = fmaxf(a2.x + bb.x, 0.0f);
        o.y = fmaxf(a2.y + bb.y, 0.0f);
        o.z = fmaxf(a2.z + bb.z, 0.0f);
        o.w = fmaxf(a2.w + bb.w, 0.0f);
        ((float4*)out)[(size_t)b * ((HG_ + HL_) / 4) + q * 8 + t] = o;
    } else if (t >= 64 && t < 96) {
        const int h = q * 32 + (t - 64);
        const float l0 = l[b * 2 + 0];
        const float l1 = l[b * 2 + 1];
        const float v = fmaf(l1, W2[HL_ + h], fmaf(l0, W2[h], b2[h]));
        out[(size_t)b * (HG_ + HL_) + HG_ + h] = fmaxf(v, 0.0f);
    }
}

extern "C" void kernel_launch(void* const* d_in, const int* in_sizes, int n_in,
                              void* d_out, int out_size, void* d_ws, size_t ws_size,
                              hipStream_t stream) {
    const float* x  = (const float*)d_in[0];
    const float* l  = (const float*)d_in[1];
    const float* W1 = (const float*)d_in[2];
    const float* b1 = (const float*)d_in[3];
    const float* W2 = (const float*)d_in[4];
    const float* b2 = (const float*)d_in[5];
    float* out = (float*)d_out;
    float* P = (float*)d_ws;                 // 288*8192 fp32 = 9.4 MB partials

    fused<<<NBLK, 256, 0, stream>>>(x, l, W1, P);
    reduce_epilogue<<<NB * 4, 256, 0, stream>>>(P, l, b1, W2, b2, out);
}

// Round 5
// 275.538 us; speedup vs baseline: 1.0147x; 1.0147x over previous
//
#include <hip/hip_runtime.h>

// Problem constants (match reference)
#define G_     64
#define NK     3
#define NB     64
#define IH     512
#define IW     512
#define NC     3
#define HG_    128
#define HL_    128
#define D_IN_    (NK * G_ * G_ * NC)   // 36864
#define D_SCALE  (G_ * G_ * NC)        // 12288
#define KCH      128                   // d per chunk (96 chunks per scale)
#define NCHUNK   (D_IN_ / KCH)         // 288
#define BSPLIT   8                     // batch groups of 8
#define NBLK     (NCHUNK * BSPLIT)     // 2304 blocks (~9/CU)
#define PSTRIDE  (NB * HG_)            // 8192 floats per chunk-slice of P

// R5: atomics were the floor -> stage-1 writes private partials.
// R6: W-load count 37.7M -> 18.9M grid-wide: 288.5 -> 278.2 us (the ONLY
//     real win so far; fused is W1-load stall/issue-bound).
// R8: LLC priming reorder: neutral (not BW-bound).
// R9: occupancy push: neutral (R9 kept W-loads at 18.9M - no lever moved).
// R10 (this round): halve W-loads AGAIN (18.9M -> 9.4M): each W-float4 read
//     ONCE per block, amortized over 8 batches (32 FMA/load). 8 d-groups of
//     16 d each; partials tree-combined via 16 KB LDS scratch (2 rounds).
template <int F>
__device__ __forceinline__ void scale_body(
    const float* __restrict__ x, const float* __restrict__ l,
    const float* __restrict__ W1, float* __restrict__ P,
    int roff, int d0, int b0, int chunkGlobal,
    float (&phi_s)[8][KCH], float4 (&scr)[4][8][HG_ / 4], int* cx_s, int* cy_s)
{
    const int tid = threadIdx.x;
    if (tid < 8) {
        float lx = l[(b0 + tid) * 2 + 0];
        float ly = l[(b0 + tid) * 2 + 1];
        // match reference: (0.5*(l+1.0)*512).astype(int32); single rounding at
        // (l+1.0f), *0.5 and *512 exact, trunc toward zero
        cx_s[tid] = (int)((0.5f * (lx + 1.0f)) * 512.0f);
        cy_s[tid] = (int)((0.5f * (ly + 1.0f)) * 512.0f);
    }
    __syncthreads();

    // ---- extraction: thread = (dd, batch-half); 4 batches per thread ----
    const int dd   = tid & (KCH - 1);
    const int jb0  = (tid >> 7) * 4;         // 0 or 4
    const int r    = roff + dd;              // within-scale: ((gy*64)+gx)*3+c
    const int gy   = r / (G_ * NC);
    const int rem  = r - gy * (G_ * NC);
    const int gx   = rem / NC;
    const int c    = rem - gx * NC;
    constexpr float inv = 1.0f / (float)(F * F);
    constexpr int JU = (F == 4) ? 2 : 4;     // keep ~16-32 loads in flight

#pragma unroll 1
    for (int jo = 0; jo < 4; jo += JU) {
        float sums[JU];
#pragma unroll
        for (int ji = 0; ji < JU; ++ji) {
            const int jb = jb0 + jo + ji;
            const int b  = b0 + jb;
            const int by = cy_s[jb] - 32 * F + gy * F;
            const int bx = cx_s[jb] - 32 * F + gx * F;
            const float* bimg = x + (size_t)b * (IH * IW * NC) + c;
            float s = 0.0f;
#pragma unroll
            for (int dy = 0; dy < F; ++dy) {
                const int y = by + dy;
                const bool yok = (unsigned)y < (unsigned)IH;
#pragma unroll
                for (int dx = 0; dx < F; ++dx) {
                    const int xx = bx + dx;
                    const bool ok = yok && ((unsigned)xx < (unsigned)IW);
                    s += ok ? bimg[(size_t)y * (IW * NC) + xx * NC] : 0.0f;
                }
            }
            sums[ji] = s;
        }
#pragma unroll
        for (int ji = 0; ji < JU; ++ji)
            phi_s[jb0 + jo + ji][dd] = sums[ji] * inv;
    }
    __syncthreads();

    // ---- GEMV v4: 256 threads = 32 h-quads x 8 d-groups (16 d each) ----
    // Each thread: ALL 8 batches x 4 h over 16 d. One W1 float4 feeds 32
    // FMAs; each W-float4 is read exactly once per block (4096/block).
    // phi reads are 32-lane-uniform (broadcast, conflict-free).
    const int hq    = tid & 31;
    const int h0    = hq * 4;
    const int dg    = tid >> 5;              // 0..7
    const int dbase = dg * 16;

    float4 acc[8];
#pragma unroll
    for (int b = 0; b < 8; ++b) acc[b] = make_float4(0.f, 0.f, 0.f, 0.f);

    const float* wp = W1 + (size_t)(d0 + dbase) * HG_ + h0;

#pragma unroll 1
    for (int t4 = 0; t4 < 4; ++t4) {
        // 4 independent W row-loads in flight
        const float4 wv0 = *(const float4*)(wp + (size_t)(4 * t4 + 0) * HG_);
        const float4 wv1 = *(const float4*)(wp + (size_t)(4 * t4 + 1) * HG_);
        const float4 wv2 = *(const float4*)(wp + (size_t)(4 * t4 + 2) * HG_);
        const float4 wv3 = *(const float4*)(wp + (size_t)(4 * t4 + 3) * HG_);
#pragma unroll
        for (int b = 0; b < 8; ++b) {
            const float4 pv = *(const float4*)&phi_s[b][dbase + 4 * t4];
            acc[b].x = fmaf(pv.x, wv0.x, acc[b].x);
            acc[b].y = fmaf(pv.x, wv0.y, acc[b].y);
            acc[b].z = fmaf(pv.x, wv0.z, acc[b].z);
            acc[b].w = fmaf(pv.x, wv0.w, acc[b].w);
            acc[b].x = fmaf(pv.y, wv1.x, acc[b].x);
            acc[b].y = fmaf(pv.y, wv1.y, acc[b].y);
            acc[b].z = fmaf(pv.y, wv1.z, acc[b].z);
            acc[b].w = fmaf(pv.y, wv1.w, acc[b].w);
            acc[b].x = fmaf(pv.z, wv2.x, acc[b].x);
            acc[b].y = fmaf(pv.z, wv2.y, acc[b].y);
            acc[b].z = fmaf(pv.z, wv2.z, acc[b].z);
            acc[b].w = fmaf(pv.z, wv2.w, acc[b].w);
            acc[b].x = fmaf(pv.w, wv3.x, acc[b].x);
            acc[b].y = fmaf(pv.w, wv3.y, acc[b].y);
            acc[b].z = fmaf(pv.w, wv3.z, acc[b].z);
            acc[b].w = fmaf(pv.w, wv3.w, acc[b].w);
        }
    }

    // ---- combine 8 d-group partials: 2 rounds over a 16 KB scratch ----
    // Round A: dg 4..7 park 4 slices; dg 0..3 add.
    if (dg >= 4) {
#pragma unroll
        for (int b = 0; b < 8; ++b) scr[dg - 4][b][hq] = acc[b];
    }
    __syncthreads();
    if (dg < 4) {
#pragma unroll
        for (int b = 0; b < 8; ++b) {
            const float4 rv = scr[dg][b][hq];
            acc[b].x += rv.x; acc[b].y += rv.y;
            acc[b].z += rv.z; acc[b].w += rv.w;
        }
    }
    __syncthreads();
    // Round B: dg 1..3 park 3 slices (reuse scratch); dg 0 adds + stores.
    if (dg >= 1 && dg < 4) {
#pragma unroll
        for (int b = 0; b < 8; ++b) scr[dg - 1][b][hq] = acc[b];
    }
    __syncthreads();
    if (dg == 0) {
        float* pb = P + (size_t)chunkGlobal * PSTRIDE + (size_t)b0 * HG_ + h0;
#pragma unroll
        for (int b = 0; b < 8; ++b) {
#pragma unroll
            for (int q = 0; q < 3; ++q) {
                const float4 rv = scr[q][b][hq];
                acc[b].x += rv.x; acc[b].y += rv.y;
                acc[b].z += rv.z; acc[b].w += rv.w;
            }
            *(float4*)(pb + (size_t)b * HG_) = acc[b];
        }
    }
}

// 2304 blocks: blockIdx = chunkGlobal*8 + bgrp.
// chunkGlobal 0..95 = F4 (dispatches first, primes LLC with the 256^2
// regions), 96..191 = F2, 192..287 = F1. d0 maps each range to its scale's
// rows of W1; P-slice index stays chunkGlobal (sum over slices is order-free).
__global__ __launch_bounds__(256, 6) void fused(
    const float* __restrict__ x, const float* __restrict__ l,
    const float* __restrict__ W1, float* __restrict__ P)
{
    __shared__ float phi_s[8][KCH];           // 4 KB
    __shared__ float4 scr[4][8][HG_ / 4];     // 16 KB (d-group combine)
    __shared__ int cx_s[8], cy_s[8];

    const int cg = blockIdx.x >> 3;
    const int b0 = (blockIdx.x & 7) * 8;

    if (cg < 96) {               // F=4 first (largest footprint)
        const int cl = cg;
        scale_body<4>(x, l, W1, P, cl * KCH, 2 * D_SCALE + cl * KCH, b0, cg,
                      phi_s, scr, cx_s, cy_s);
    } else if (cg < 192) {       // F=2
        const int cl = cg - 96;
        scale_body<2>(x, l, W1, P, cl * KCH, D_SCALE + cl * KCH, b0, cg,
                      phi_s, scr, cx_s, cy_s);
    } else {                     // F=1
        const int cl = cg - 192;
        scale_body<1>(x, l, W1, P, cl * KCH, cl * KCH, b0, cg,
                      phi_s, scr, cx_s, cy_s);
    }
}

// Stage 2: 256 blocks = (batch x h-quarter); all CUs participate.
// 256 threads = 32 groups x 8 float4-lanes; each thread sums 9 chunk
// partials (float4), LDS tree combine over groups, 8 threads emit the phi
// quarter, threads 64..95 emit the matching l-branch quarter.
__global__ __launch_bounds__(256) void reduce_epilogue(
    const float* __restrict__ P,
    const float* __restrict__ l,
    const float* __restrict__ b1,
    const float* __restrict__ W2,
    const float* __restrict__ b2,
    float* __restrict__ out)
{
    __shared__ float4 red[32][8];        // 4 KB
    const int b    = blockIdx.x >> 2;
    const int q    = blockIdx.x & 3;     // h-quarter: h0 = q*32
    const int t    = threadIdx.x;
    const int lane = t & 7;              // float4 lane within the 32-h strip
    const int grp  = t >> 3;             // 0..31, 9 chunks each

    const float4* p4 = (const float4*)P
                     + (size_t)(grp * 9) * (PSTRIDE / 4)
                     + (size_t)b * (HG_ / 4) + q * 8 + lane;
    float4 a = make_float4(0.f, 0.f, 0.f, 0.f);
#pragma unroll
    for (int i = 0; i < 9; ++i) {
        const float4 v = p4[(size_t)i * (PSTRIDE / 4)];
        a.x += v.x; a.y += v.y; a.z += v.z; a.w += v.w;
    }
    red[grp][lane] = a;
    __syncthreads();

#pragma unroll
    for (int s = 16; s >= 1; s >>= 1) {
        if (grp < s) {
            const float4 o = red[grp + s][lane];
            float4 m = red[grp][lane];
            m.x += o.x; m.y += o.y; m.z += o.z; m.w += o.w;
            red[grp][lane] = m;
        }
        __syncthreads();
    }

    if (t < 8) {
        const float4 a2 = red[0][t];
        const float4 bb = ((const float4*)b1)[q * 8 + t];
        float4 o;
        o.x = fmaxf(a2.x + bb.x, 0.0f);
        o.y = fmaxf(a2.y + bb.y, 0.0f);
        o.z = fmaxf(a2.z + bb.z, 0.0f);
        o.w = fmaxf(a2.w + bb.w, 0.0f);
        ((float4*)out)[(size_t)b * ((HG_ + HL_) / 4) + q * 8 + t] = o;
    } else if (t >= 64 && t < 96) {
        const int h = q * 32 + (t - 64);
        const float l0 = l[b * 2 + 0];
        const float l1 = l[b * 2 + 1];
        const float v = fmaf(l1, W2[HL_ + h], fmaf(l0, W2[h], b2[h]));
        out[(size_t)b * (HG_ + HL_) + HG_ + h] = fmaxf(v, 0.0f);
    }
}

extern "C" void kernel_launch(void* const* d_in, const int* in_sizes, int n_in,
                              void* d_out, int out_size, void* d_ws, size_t ws_size,
                              hipStream_t stream) {
    const float* x  = (const float*)d_in[0];
    const float* l  = (const float*)d_in[1];
    const float* W1 = (const float*)d_in[2];
    const float* b1 = (const float*)d_in[3];
    const float* W2 = (const float*)d_in[4];
    const float* b2 = (const float*)d_in[5];
    float* out = (float*)d_out;
    float* P = (float*)d_ws;                 // 288*8192 fp32 = 9.4 MB partials

    fused<<<NBLK, 256, 0, stream>>>(x, l, W1, P);
    reduce_epilogue<<<NB * 4, 256, 0, stream>>>(P, l, b1, W2, b2, out);
}